// Round 6
// baseline (2243.764 us; speedup 1.0000x reference)
//
#include <hip/hip_runtime.h>

// ---------------- problem constants ----------------
#define BB 128
#define NN 4096
#define DD 64
#define SS 7
#define HH 128
#define N_ITERS 3
#define EPS_ATTN 1e-8f
#define LN_EPS 1e-5f

typedef unsigned short ushortT;
using short8  = __attribute__((ext_vector_type(8))) short;
using floatx4 = __attribute__((ext_vector_type(4))) float;
using uint4v  = __attribute__((ext_vector_type(4))) unsigned;

__device__ __forceinline__ ushortT f2bf(float f) {
    unsigned x = __builtin_bit_cast(unsigned, f);
    x = x + 0x7fff + ((x >> 16) & 1);   // RNE
    return (ushortT)(x >> 16);
}
__device__ __forceinline__ void wave_stats64(float x, float& mu, float& var) {
    float s1 = x, s2 = x * x;
#pragma unroll
    for (int off = 32; off > 0; off >>= 1) {
        s1 += __shfl_xor(s1, off);
        s2 += __shfl_xor(s2, off);
    }
    mu  = s1 * (1.f / 64.f);
    var = s2 * (1.f / 64.f) - mu * mu;
}
__device__ __forceinline__ void st_agent(float* p, float v) {
    __hip_atomic_store(p, v, __ATOMIC_RELAXED, __HIP_MEMORY_SCOPE_AGENT);
}
__device__ __forceinline__ float ld_agent(const float* p) {
    return __hip_atomic_load((float*)p, __ATOMIC_RELAXED, __HIP_MEMORY_SCOPE_AGENT);
}

// ---------------- D1: weight transposes + ticket zero ----------------
__global__ void prep_zero(const float* __restrict__ Wih, const float* __restrict__ Whh,
                          const float* __restrict__ w1, const float* __restrict__ w2,
                          const float* __restrict__ Wv,
                          float* __restrict__ WihT, float* __restrict__ WhhT,
                          float* __restrict__ w1T, float* __restrict__ w2T,
                          float* __restrict__ WvT, int* __restrict__ tick) {
    if (blockIdx.x >= 176) {
        int i = (blockIdx.x - 176) * 256 + threadIdx.x;
        if (i < 384) tick[i] = 0;
        return;
    }
    int i = blockIdx.x * 256 + threadIdx.x;   // < 45056
    if (i < 12288) {
        int e = i >> 6, d = i & 63;
        WihT[d * 192 + e] = Wih[i];
    } else if (i < 24576) {
        int j = i - 12288; int e = j >> 6, d = j & 63;
        WhhT[d * 192 + e] = Whh[j];
    } else if (i < 32768) {
        int j = i - 24576; int e = j >> 6, d = j & 63;   // w1 [128][64]
        w1T[d * 128 + e] = w1[j];
    } else if (i < 40960) {
        int j = i - 32768; int e = j >> 7, h = j & 127;  // w2 [64][128]
        w2T[h * 64 + e] = w2[j];
    } else if (i < 45056) {
        int j = i - 40960; int d = j >> 6, e = j & 63;   // Wv [d][e] -> WvT [e][d]
        WvT[e * 64 + d] = Wv[j];
    }
}

// ---------------- D2/D3/D4: attn + ticket-gated slot update ----------------
// Grid 4096, 256 thr. Block ck: batch bt=ck>>5, chunk c=ck&31 (128 rows).
// it==0: slot-init + qk computed redundantly per block (LDS), LN(x)->xw+xnf.
// else : xw from xnf, qk frags from qk_bf (prev dispatch's winners).
// Attn body = proven R3 kernel. Partials -> agent(sc1) stores; ticket
// atomicAdd picks the LAST block of the batch, which performs the full
// 7-slot GRU/LN/MLP update and emits slots+qk_bf (it<2) or outp (it==2).
__global__ __launch_bounds__(256, 2) void attn_slot(
    int it,
    const float* __restrict__ x,
    const float* __restrict__ lngi, const float* __restrict__ lnbi,
    ushortT* __restrict__ xnf, ushortT* __restrict__ qk_bf,
    float* __restrict__ slots, float* __restrict__ outp,
    const float* __restrict__ nbg, const float* __restrict__ nfg,
    const float* __restrict__ bgmu, const float* __restrict__ bgls,
    const float* __restrict__ fmu, const float* __restrict__ fls,
    const float* __restrict__ Wq, const float* __restrict__ Wk,
    const float* __restrict__ WihT, const float* __restrict__ WhhT,
    const float* __restrict__ bih, const float* __restrict__ bhh,
    const float* __restrict__ lnmg, const float* __restrict__ lnmb,
    const float* __restrict__ w1T, const float* __restrict__ b1,
    const float* __restrict__ w2T, const float* __restrict__ b2,
    const float* __restrict__ WvT,
    const float* __restrict__ sg, const float* __restrict__ sb,
    float* __restrict__ pxn_p, float* __restrict__ den_p,
    int* __restrict__ tick) {
    int t = threadIdx.x;
    int ck = blockIdx.x, bt = ck >> 5;
    int w = t >> 6, lane = t & 63, m = lane & 15, qd = lane >> 4;

    // time-multiplexed LDS union (phases barrier-separated)
    __shared__ __align__(16) char smem[23424];
    ushortT* xnT = (ushortT*)smem;                           // [64*140]   attn
    ushortT (*p_lds)[136] = (ushortT(*)[136])(smem + 17920); // [16][136]  attn
    float* qk0S = (float*)smem;                              // [8][64]    it0 pre
    float* sL   = (float*)(smem + 2048);                     // [7][64]    it0 pre
    float* xnqS = (float*)(smem + 3840);                     // [7][64]    it0 pre
    float* qS   = (float*)(smem + 5632);                     // [7][64]    it0 pre
    float* pxnS = (float*)smem;                              // [7][64]    tail
    float* updS = (float*)(smem + 1792);                     // [7][64]    tail
    float* hpS  = (float*)(smem + 3584);                     // [7][64]    tail
    float* giS  = (float*)(smem + 5376);                     // [7][192]   tail
    float* ghS  = (float*)(smem + 10752);                    // [7][192]   tail
    float* m1S  = (float*)(smem + 16128);                    // [7][128]   tail
    float* resS = (float*)(smem + 19712);                    // [7][64]    tail
    float* mnS  = (float*)(smem + 21504);                    // [7][64]    tail
    __shared__ float denS[8];
    __shared__ int winflag;

    // ---- it0: redundant slot-init + qk (per block, identical across blocks) ----
    float sinit0 = 0.f, sinit1 = 0.f;
    if (it == 0) {
        {
            int s = t >> 6, d = t & 63;
            sinit0 = (s == 0) ? bgmu[d] + __expf(bgls[d]) * nbg[bt * 64 + d]
                              : fmu[d]  + __expf(fls[d])  * nfg[(bt * 6 + s - 1) * 64 + d];
            sL[t] = sinit0;
            if (t < 192) {
                int i2 = 256 + t; int s2 = i2 >> 6, d2 = i2 & 63;   // s2 in 4..6
                sinit1 = fmu[d2] + __expf(fls[d2]) * nfg[(bt * 6 + s2 - 1) * 64 + d2];
                sL[i2] = sinit1;
            }
        }
        __syncthreads();
        for (int s2 = w; s2 < 7; s2 += 4) {
            float v = sL[s2 * 64 + lane], mu, var;
            wave_stats64(v, mu, var);
            xnqS[s2 * 64 + lane] = (v - mu) * rsqrtf(var + LN_EPS) * sg[lane] + sb[lane];
        }
        __syncthreads();
#pragma unroll
        for (int p = 0; p < 2; ++p) {
            int i = p * 256 + t;
            if (i < 448) {
                int s = i >> 6, e = i & 63; float a = 0.f;
#pragma unroll 8
                for (int d = 0; d < 64; ++d) a += xnqS[s * 64 + d] * Wq[e * 64 + d];
                qS[i] = a;
            }
        }
        __syncthreads();
#pragma unroll
        for (int p = 0; p < 2; ++p) {
            int i = p * 256 + t;
            if (i < 448) {
                int s = i >> 6, t2 = i & 63; float a = 0.f;
#pragma unroll 8
                for (int e = 0; e < 64; ++e) a += qS[s * 64 + e] * Wk[e * 64 + t2];
                qk0S[i] = 0.125f * a;
            } else {
                qk0S[i] = 0.f;   // slot 7
            }
        }
        __syncthreads();
    }

    // ---- A-frags: qk^T, slots x dims ----
    short8 aq0 = {}, aq1 = {};
    if (it == 0) {
        if (m < 8) {
#pragma unroll
            for (int j = 0; j < 8; ++j) {
                aq0[j] = (short)f2bf(qk0S[m * 64 + qd * 8 + j]);
                aq1[j] = (short)f2bf(qk0S[m * 64 + 32 + qd * 8 + j]);
            }
        }
        __syncthreads();   // qk0S region about to be overwritten by xnT
    } else {
        if (m < 8) {
            const ushortT* qb = qk_bf + bt * 512 + m * 64 + qd * 8;
            aq0 = *reinterpret_cast<const short8*>(qb);
            aq1 = *reinterpret_cast<const short8*>(qb + 32);
        }
    }

    // ---- xw: LN(x) (it0, + write xnf) or load xnf ----
    unsigned xw[2][8];
    if (it == 0) {
        float4 g4[2][2], b4[2][2];
#pragma unroll
        for (int c = 0; c < 2; ++c) {
            g4[c][0] = *reinterpret_cast<const float4*>(lngi + c * 32 + qd * 8);
            g4[c][1] = *reinterpret_cast<const float4*>(lngi + c * 32 + qd * 8 + 4);
            b4[c][0] = *reinterpret_cast<const float4*>(lnbi + c * 32 + qd * 8);
            b4[c][1] = *reinterpret_cast<const float4*>(lnbi + c * 32 + qd * 8 + 4);
        }
#pragma unroll
        for (int tile = 0; tile < 2; ++tile) {
            long R = (long)ck * 128 + w * 32 + tile * 16 + m;
            float4 xa[2][2];
#pragma unroll
            for (int c = 0; c < 2; ++c) {
                xa[c][0] = *reinterpret_cast<const float4*>(x + R * 64 + c * 32 + qd * 8);
                xa[c][1] = *reinterpret_cast<const float4*>(x + R * 64 + c * 32 + qd * 8 + 4);
            }
            float s1 = 0.f, s2 = 0.f;
#pragma unroll
            for (int c = 0; c < 2; ++c)
#pragma unroll
                for (int h = 0; h < 2; ++h) {
                    float4 v = xa[c][h];
                    s1 += v.x + v.y + v.z + v.w;
                    s2 += v.x * v.x + v.y * v.y + v.z * v.z + v.w * v.w;
                }
            s1 += __shfl_xor(s1, 16); s2 += __shfl_xor(s2, 16);
            s1 += __shfl_xor(s1, 32); s2 += __shfl_xor(s2, 32);
            float mu = s1 * (1.f / 64.f);
            float var = s2 * (1.f / 64.f) - mu * mu;
            float rs = rsqrtf(var + LN_EPS);
#pragma unroll
            for (int c = 0; c < 2; ++c)
#pragma unroll
                for (int h = 0; h < 2; ++h) {
                    float n0 = (xa[c][h].x - mu) * rs * g4[c][h].x + b4[c][h].x;
                    float n1 = (xa[c][h].y - mu) * rs * g4[c][h].y + b4[c][h].y;
                    float n2 = (xa[c][h].z - mu) * rs * g4[c][h].z + b4[c][h].z;
                    float n3 = (xa[c][h].w - mu) * rs * g4[c][h].w + b4[c][h].w;
                    xw[tile][c * 4 + h * 2]     = (unsigned)f2bf(n0) | ((unsigned)f2bf(n1) << 16);
                    xw[tile][c * 4 + h * 2 + 1] = (unsigned)f2bf(n2) | ((unsigned)f2bf(n3) << 16);
                }
            ushortT* xp = xnf + (long)ck * 8192 + w * 2048 + tile * 1024 + lane * 16;
            *reinterpret_cast<uint4*>(xp) =
                make_uint4(xw[tile][0], xw[tile][1], xw[tile][2], xw[tile][3]);
            *reinterpret_cast<uint4*>(xp + 8) =
                make_uint4(xw[tile][4], xw[tile][5], xw[tile][6], xw[tile][7]);
        }
    } else {
#pragma unroll
        for (int tile = 0; tile < 2; ++tile) {
            const ushortT* xp = xnf + (long)ck * 8192 + w * 2048 + tile * 1024 + lane * 16;
            uint4 u0 = *reinterpret_cast<const uint4*>(xp);
            uint4 u1 = *reinterpret_cast<const uint4*>(xp + 8);
            xw[tile][0] = u0.x; xw[tile][1] = u0.y; xw[tile][2] = u0.z; xw[tile][3] = u0.w;
            xw[tile][4] = u1.x; xw[tile][5] = u1.y; xw[tile][6] = u1.z; xw[tile][7] = u1.w;
        }
    }

    // ---- scatter xn into xnT (pair-packed b32, proven R3 path) ----
#pragma unroll
    for (int tile = 0; tile < 2; ++tile) {
        int Re = (w * 32 + tile * 16 + m) & ~1;
#pragma unroll
        for (int c = 0; c < 2; ++c) {
            unsigned pt[4];
#pragma unroll
            for (int k = 0; k < 4; ++k) pt[k] = __shfl_xor(xw[tile][c * 4 + k], 1);
#pragma unroll
            for (int kk = 0; kk < 2; ++kk) {
                unsigned own = (m & 1) ? xw[tile][c * 4 + 2 + kk] : xw[tile][c * 4 + kk];
                unsigned par = (m & 1) ? pt[2 + kk] : pt[kk];
                unsigned a   = (m & 1) ? par : own;
                unsigned bb  = (m & 1) ? own : par;
                unsigned lo = (a & 0xffffu) | (bb << 16);
                unsigned hi = (a >> 16)     | (bb & 0xffff0000u);
                int e = c * 32 + qd * 8 + 2 * kk + ((m & 1) ? 4 : 0);
                *reinterpret_cast<unsigned*>(&xnT[e * 140 + Re])       = lo;
                *reinterpret_cast<unsigned*>(&xnT[(e + 1) * 140 + Re]) = hi;
            }
        }
    }

    // ---- phase 1: logits ----
    floatx4 accT0 = {0.f, 0.f, 0.f, 0.f}, accT1 = {0.f, 0.f, 0.f, 0.f};
    {
        uint4v b00 = {xw[0][0], xw[0][1], xw[0][2], xw[0][3]};
        uint4v b01 = {xw[0][4], xw[0][5], xw[0][6], xw[0][7]};
        accT0 = __builtin_amdgcn_mfma_f32_16x16x32_bf16(aq0,
                    __builtin_bit_cast(short8, b00), accT0, 0, 0, 0);
        accT0 = __builtin_amdgcn_mfma_f32_16x16x32_bf16(aq1,
                    __builtin_bit_cast(short8, b01), accT0, 0, 0, 0);
        uint4v b10 = {xw[1][0], xw[1][1], xw[1][2], xw[1][3]};
        uint4v b11 = {xw[1][4], xw[1][5], xw[1][6], xw[1][7]};
        accT1 = __builtin_amdgcn_mfma_f32_16x16x32_bf16(aq0,
                    __builtin_bit_cast(short8, b10), accT1, 0, 0, 0);
        accT1 = __builtin_amdgcn_mfma_f32_16x16x32_bf16(aq1,
                    __builtin_bit_cast(short8, b11), accT1, 0, 0, 0);
    }

    // ---- tile-split softmax ----
    float lgA[4], lgB[4];
#pragma unroll
    for (int r = 0; r < 4; ++r) {
        float hi = __shfl_xor(accT1[r], 32);
        float wk = (qd < 2) ? accT0[r] : hi;
        float pr = __shfl_xor(wk, 16);
        lgA[r] = (qd & 1) ? pr : wk;
        lgB[r] = (qd & 1) ? wk : pr;
    }
    float mx = fmaxf(fmaxf(fmaxf(lgA[0], lgA[1]), fmaxf(lgA[2], lgA[3])),
                     fmaxf(fmaxf(lgB[0], lgB[1]), lgB[2]));
    float eA[4], eB[3], sum = 0.f;
#pragma unroll
    for (int r = 0; r < 4; ++r) { eA[r] = __expf(lgA[r] - mx); sum += eA[r]; }
#pragma unroll
    for (int r = 0; r < 3; ++r) { eB[r] = __expf(lgB[r] - mx); sum += eB[r]; }
    float inv = 1.f / sum;
    int prow = w * 32 + (qd >> 1) * 16 + m;
    if ((qd & 1) == 0) {
#pragma unroll
        for (int r = 0; r < 4; ++r) p_lds[r][prow] = f2bf(eA[r] * inv + EPS_ATTN);
    } else {
#pragma unroll
        for (int r = 0; r < 3; ++r) p_lds[4 + r][prow] = f2bf(eB[r] * inv + EPS_ATTN);
    }
    __syncthreads();

    // ---- phase 2: pxn / den via MFMA ----
    short8 ones;
#pragma unroll
    for (int j = 0; j < 8; ++j) ones[j] = (short)0x3F80;
    floatx4 acc2 = {0.f, 0.f, 0.f, 0.f}, accd = {0.f, 0.f, 0.f, 0.f};
#pragma unroll
    for (int ks = 0; ks < 4; ++ks) {
        short8 ap = *reinterpret_cast<const short8*>(&p_lds[m][ks * 32 + qd * 8]);
        const ushortT* xp = xnT + (w * 16 + m) * 140 + ks * 32 + qd * 8;
        uint2 u0 = *reinterpret_cast<const uint2*>(xp);
        uint2 u1 = *reinterpret_cast<const uint2*>(xp + 4);
        uint4v bb = {u0.x, u0.y, u1.x, u1.y};
        acc2 = __builtin_amdgcn_mfma_f32_16x16x32_bf16(ap,
                   __builtin_bit_cast(short8, bb), acc2, 0, 0, 0);
        accd = __builtin_amdgcn_mfma_f32_16x16x32_bf16(ap, ones, accd, 0, 0, 0);
    }
    // partials -> MALL (sc1), then ticket
#pragma unroll
    for (int r = 0; r < 4; ++r) {
        int s = qd * 4 + r;
        if (s < 7) st_agent(&pxn_p[((long)ck * 7 + s) * 64 + w * 16 + m], acc2[r]);
    }
    if (w == 0 && m == 0) {
#pragma unroll
        for (int r = 0; r < 4; ++r) {
            int s = qd * 4 + r;
            if (s < 7) st_agent(&den_p[ck * 8 + s], accd[r]);
        }
    }
    __threadfence();
    __syncthreads();
    if (t == 0) {
        int old = atomicAdd(&tick[it * 128 + bt], 1);
        winflag = (old == 31);
    }
    __syncthreads();
    if (!winflag) return;
    __threadfence();

    // ================= winner: full slot update for batch bt =================
    // hprev
    if (it == 0) {
        hpS[t] = sinit0;
        if (t < 192) hpS[256 + t] = sinit1;
    } else {
#pragma unroll
        for (int p = 0; p < 2; ++p) {
            int i = p * 256 + t;
            if (i < 448) hpS[i] = slots[(long)bt * 448 + i];
        }
    }
    // pxn reduce over 32 chunks + den
#pragma unroll
    for (int p = 0; p < 2; ++p) {
        int i = p * 256 + t;
        if (i < 448) {
            int s = i >> 6, e = i & 63;
            float acc = 0.f;
#pragma unroll 8
            for (int c = 0; c < 32; ++c)
                acc += ld_agent(&pxn_p[((long)(bt * 32 + c) * 7 + s) * 64 + e]);
            pxnS[i] = acc;
        }
    }
    if (t < 7) {
        float d = 0.f;
#pragma unroll 8
        for (int c = 0; c < 32; ++c) d += ld_agent(&den_p[(bt * 32 + c) * 8 + t]);
        denS[t] = d;
    }
    __syncthreads();
    // upd = (pxn . WvT) / den
#pragma unroll
    for (int p = 0; p < 2; ++p) {
        int i = p * 256 + t;
        if (i < 448) {
            int s = i >> 6, d = i & 63;
            float a = 0.f;
#pragma unroll 8
            for (int e = 0; e < 64; ++e) a += pxnS[s * 64 + e] * WvT[e * 64 + d];
            updS[i] = a / denS[s];
        }
    }
    __syncthreads();
    // GRU gates
#pragma unroll
    for (int p = 0; p < 6; ++p) {
        int i = p * 256 + t;
        if (i < 1344) {
            int s = i / 192, g = i % 192;
            float a = bih[g], h2 = bhh[g];
#pragma unroll 8
            for (int d = 0; d < 64; ++d) {
                a  += updS[s * 64 + d] * WihT[d * 192 + g];
                h2 += hpS[s * 64 + d]  * WhhT[d * 192 + g];
            }
            giS[i] = a; ghS[i] = h2;
        }
    }
    __syncthreads();
    // gate combine
#pragma unroll
    for (int p = 0; p < 2; ++p) {
        int i = p * 256 + t;
        if (i < 448) {
            int s = i >> 6, d = i & 63;
            float r = 1.f / (1.f + __expf(-(giS[s * 192 + d] + ghS[s * 192 + d])));
            float z = 1.f / (1.f + __expf(-(giS[s * 192 + 64 + d] + ghS[s * 192 + 64 + d])));
            float n = tanhf(giS[s * 192 + 128 + d] + r * ghS[s * 192 + 128 + d]);
            resS[i] = (1.f - z) * n + z * hpS[i];
        }
    }
    __syncthreads();
    // LN_mlp
    for (int s2 = w; s2 < 7; s2 += 4) {
        float v = resS[s2 * 64 + lane], mu, var;
        wave_stats64(v, mu, var);
        mnS[s2 * 64 + lane] = (v - mu) * rsqrtf(var + LN_EPS) * lnmg[lane] + lnmb[lane];
    }
    __syncthreads();
    // MLP1
#pragma unroll
    for (int p = 0; p < 4; ++p) {
        int i = p * 256 + t;
        if (i < 896) {
            int s = i >> 7, h1 = i & 127;
            float a = b1[h1];
#pragma unroll 8
            for (int d = 0; d < 64; ++d) a += mnS[s * 64 + d] * w1T[d * 128 + h1];
            m1S[i] = fmaxf(a, 0.f);
        }
    }
    __syncthreads();
    // MLP2 + residual
#pragma unroll
    for (int p = 0; p < 2; ++p) {
        int i = p * 256 + t;
        if (i < 448) {
            int s = i >> 6, d = i & 63;
            float a = b2[d];
#pragma unroll 8
            for (int h2 = 0; h2 < 128; ++h2) a += m1S[s * 128 + h2] * w2T[h2 * 64 + d];
            resS[i] += a;
        }
    }
    __syncthreads();
    if (it == 2) {
#pragma unroll
        for (int p = 0; p < 2; ++p) {
            int i = p * 256 + t;
            if (i < 448) outp[(long)bt * 448 + i] = resS[i];
        }
        return;
    }
#pragma unroll
    for (int p = 0; p < 2; ++p) {
        int i = p * 256 + t;
        if (i < 448) slots[(long)bt * 448 + i] = resS[i];
    }
    // slot LN -> updS (reuse)
    for (int s2 = w; s2 < 7; s2 += 4) {
        float v = resS[s2 * 64 + lane], mu, var;
        wave_stats64(v, mu, var);
        updS[s2 * 64 + lane] = (v - mu) * rsqrtf(var + LN_EPS) * sg[lane] + sb[lane];
    }
    __syncthreads();
    // q -> pxnS (reuse)
#pragma unroll
    for (int p = 0; p < 2; ++p) {
        int i = p * 256 + t;
        if (i < 448) {
            int s = i >> 6, e = i & 63;
            float a = 0.f;
#pragma unroll 8
            for (int d = 0; d < 64; ++d) a += updS[s * 64 + d] * Wq[e * 64 + d];
            pxnS[i] = a;
        }
    }
    __syncthreads();
    // qk -> qk_bf (bf16), slot 7 zeroed
#pragma unroll
    for (int p = 0; p < 2; ++p) {
        int i = p * 256 + t;
        if (i < 448) {
            int s = i >> 6, t2 = i & 63;
            float a = 0.f;
#pragma unroll 8
            for (int e = 0; e < 64; ++e) a += pxnS[s * 64 + e] * Wk[e * 64 + t2];
            qk_bf[(long)bt * 512 + i] = f2bf(0.125f * a);
        } else {
            qk_bf[(long)bt * 512 + i] = 0;
        }
    }
}

// ---------------- launcher: 4 dispatches ----------------
extern "C" void kernel_launch(void* const* d_in, const int* in_sizes, int n_in,
                              void* d_out, int out_size, void* d_ws, size_t ws_size,
                              hipStream_t stream) {
    const float* inputs    = (const float*)d_in[0];
    const float* noise_bg  = (const float*)d_in[1];
    const float* noise_fg  = (const float*)d_in[2];
    const float* ln_in_g   = (const float*)d_in[3];
    const float* ln_in_b   = (const float*)d_in[4];
    const float* ln_slot_g = (const float*)d_in[5];
    const float* ln_slot_b = (const float*)d_in[6];
    const float* ln_mlp_g  = (const float*)d_in[7];
    const float* ln_mlp_b  = (const float*)d_in[8];
    const float* Wq        = (const float*)d_in[9];
    const float* Wk        = (const float*)d_in[10];
    const float* Wv        = (const float*)d_in[11];
    const float* W_ih      = (const float*)d_in[12];
    const float* W_hh      = (const float*)d_in[13];
    const float* b_ih      = (const float*)d_in[14];
    const float* b_hh      = (const float*)d_in[15];
    const float* mlp_w1    = (const float*)d_in[16];
    const float* mlp_b1    = (const float*)d_in[17];
    const float* mlp_w2    = (const float*)d_in[18];
    const float* mlp_b2    = (const float*)d_in[19];
    const float* sbg_mu    = (const float*)d_in[20];
    const float* sbg_ls    = (const float*)d_in[21];
    const float* s_mu      = (const float*)d_in[22];
    const float* s_ls      = (const float*)d_in[23];

    char* ws = (char*)d_ws;
    size_t off = 0;
    auto alloc = [&](size_t bytes) {
        void* p = ws + off;
        off += (bytes + 255) & ~(size_t)255;
        return p;
    };
    ushortT* xnf   = (ushortT*)alloc((size_t)BB * NN * 64 * 2);   // 64 MiB bf16 xn
    float* slots   = (float*)alloc((size_t)BB * 7 * 64 * 4);
    ushortT* qk_bf = (ushortT*)alloc((size_t)BB * 512 * 2);
    float* pxn_p   = (float*)alloc((size_t)4096 * 7 * 64 * 4);
    float* den_p   = (float*)alloc(4096 * 8 * 4);
    float* WihT    = (float*)alloc(12288 * 4);
    float* WhhT    = (float*)alloc(12288 * 4);
    float* w1T     = (float*)alloc(8192 * 4);
    float* w2T     = (float*)alloc(8192 * 4);
    float* WvT     = (float*)alloc(4096 * 4);
    int*   tick    = (int*)alloc(384 * 4);
    if (off > ws_size) return;
    float* outp = (float*)d_out;

    prep_zero<<<178, 256, 0, stream>>>(W_ih, W_hh, mlp_w1, mlp_w2, Wv,
                                       WihT, WhhT, w1T, w2T, WvT, tick);
    for (int it = 0; it < N_ITERS; ++it) {
        attn_slot<<<4096, 256, 0, stream>>>(
            it, inputs, ln_in_g, ln_in_b, xnf, qk_bf, slots, outp,
            noise_bg, noise_fg, sbg_mu, sbg_ls, s_mu, s_ls,
            Wq, Wk, WihT, WhhT, b_ih, b_hh,
            ln_mlp_g, ln_mlp_b, w1T, mlp_b1, w2T, mlp_b2,
            WvT, ln_slot_g, ln_slot_b,
            pxn_p, den_p, tick);
    }
}

// Round 7
// 750.797 us; speedup vs baseline: 2.9885x; 2.9885x over previous
//
#include <hip/hip_runtime.h>

// ---------------- problem constants ----------------
#define BB 128
#define NN 4096
#define DD 64
#define SS 7
#define HH 128
#define N_ITERS 3
#define EPS_ATTN 1e-8f
#define LN_EPS 1e-5f

typedef unsigned short ushortT;
using short8  = __attribute__((ext_vector_type(8))) short;
using floatx4 = __attribute__((ext_vector_type(4))) float;
using uint4v  = __attribute__((ext_vector_type(4))) unsigned;

__device__ __forceinline__ ushortT f2bf(float f) {
    unsigned x = __builtin_bit_cast(unsigned, f);
    x = x + 0x7fff + ((x >> 16) & 1);   // RNE
    return (ushortT)(x >> 16);
}
__device__ __forceinline__ void wave_stats64(float x, float& mu, float& var) {
    float s1 = x, s2 = x * x;
#pragma unroll
    for (int off = 32; off > 0; off >>= 1) {
        s1 += __shfl_xor(s1, off);
        s2 += __shfl_xor(s2, off);
    }
    mu  = s1 * (1.f / 64.f);
    var = s2 * (1.f / 64.f) - mu * mu;
}
__device__ __forceinline__ float ld_agent(const float* p) {
    return __hip_atomic_load((float*)p, __ATOMIC_RELAXED, __HIP_MEMORY_SCOPE_AGENT);
}

// ---------------- D1: weight transposes + accumulator/ticket zero ----------------
// zero region = pxn_acc(172032) + den_acc(3072) + tick(384) = 175488 words, contiguous.
__global__ void prep_zero(const float* __restrict__ Wih, const float* __restrict__ Whh,
                          const float* __restrict__ w1, const float* __restrict__ w2,
                          const float* __restrict__ Wv,
                          float* __restrict__ WihT, float* __restrict__ WhhT,
                          float* __restrict__ w1T, float* __restrict__ w2T,
                          float* __restrict__ WvT, float* __restrict__ zbase) {
    if (blockIdx.x >= 176) {
        int i = (blockIdx.x - 176) * 256 + threadIdx.x;
        if (i < 175488) zbase[i] = 0.f;
        return;
    }
    int i = blockIdx.x * 256 + threadIdx.x;   // < 45056
    if (i < 12288) {
        int e = i >> 6, d = i & 63;
        WihT[d * 192 + e] = Wih[i];
    } else if (i < 24576) {
        int j = i - 12288; int e = j >> 6, d = j & 63;
        WhhT[d * 192 + e] = Whh[j];
    } else if (i < 32768) {
        int j = i - 24576; int e = j >> 6, d = j & 63;   // w1 [128][64]
        w1T[d * 128 + e] = w1[j];
    } else if (i < 40960) {
        int j = i - 32768; int e = j >> 7, h = j & 127;  // w2 [64][128]
        w2T[h * 64 + e] = w2[j];
    } else if (i < 45056) {
        int j = i - 40960; int d = j >> 6, e = j & 63;   // Wv [d][e] -> WvT [e][d]
        WvT[e * 64 + d] = Wv[j];
    }
}

// ---------------- D2/D3/D4: attn + ticket-gated slot update ----------------
// Grid 4096, 256 thr. Block ck: batch bt=ck>>5, chunk c=ck&31 (128 rows).
// Partials accumulate via MALL atomicAdd (device-coherent, no fence, no wbl2);
// per-wave vmcnt(0) drain + relaxed ticket picks the LAST block of the batch,
// which performs the full 7-slot GRU/LN/MLP update (reads accs via sc0sc1).
__global__ __launch_bounds__(256, 2) void attn_slot(
    int it,
    const float* __restrict__ x,
    const float* __restrict__ lngi, const float* __restrict__ lnbi,
    ushortT* __restrict__ xnf, ushortT* __restrict__ qk_bf,
    float* __restrict__ slots, float* __restrict__ outp,
    const float* __restrict__ nbg, const float* __restrict__ nfg,
    const float* __restrict__ bgmu, const float* __restrict__ bgls,
    const float* __restrict__ fmu, const float* __restrict__ fls,
    const float* __restrict__ Wq, const float* __restrict__ Wk,
    const float* __restrict__ WihT, const float* __restrict__ WhhT,
    const float* __restrict__ bih, const float* __restrict__ bhh,
    const float* __restrict__ lnmg, const float* __restrict__ lnmb,
    const float* __restrict__ w1T, const float* __restrict__ b1,
    const float* __restrict__ w2T, const float* __restrict__ b2,
    const float* __restrict__ WvT,
    const float* __restrict__ sg, const float* __restrict__ sb,
    float* __restrict__ pxn_acc, float* __restrict__ den_acc,
    int* __restrict__ tick) {
    int t = threadIdx.x;
    int ck = blockIdx.x, bt = ck >> 5;
    int w = t >> 6, lane = t & 63, m = lane & 15, qd = lane >> 4;

    // time-multiplexed LDS union (phases barrier-separated)
    __shared__ __align__(16) char smem[23424];
    ushortT* xnT = (ushortT*)smem;                           // [64*140]   attn
    ushortT (*p_lds)[136] = (ushortT(*)[136])(smem + 17920); // [16][136]  attn
    float* qk0S = (float*)smem;                              // [8][64]    it0 pre
    float* sL   = (float*)(smem + 2048);                     // [7][64]    it0 pre
    float* xnqS = (float*)(smem + 3840);                     // [7][64]    it0 pre
    float* qS   = (float*)(smem + 5632);                     // [7][64]    it0 pre
    float* pxnS = (float*)smem;                              // [7][64]    tail
    float* updS = (float*)(smem + 1792);                     // [7][64]    tail
    float* hpS  = (float*)(smem + 3584);                     // [7][64]    tail
    float* giS  = (float*)(smem + 5376);                     // [7][192]   tail
    float* ghS  = (float*)(smem + 10752);                    // [7][192]   tail
    float* m1S  = (float*)(smem + 16128);                    // [7][128]   tail
    float* resS = (float*)(smem + 19712);                    // [7][64]    tail
    float* mnS  = (float*)(smem + 21504);                    // [7][64]    tail
    __shared__ float denS[8];
    __shared__ int winflag;

    // ---- it0: redundant slot-init + qk (per block, identical across blocks) ----
    float sinit0 = 0.f, sinit1 = 0.f;
    if (it == 0) {
        {
            int s = t >> 6, d = t & 63;
            sinit0 = (s == 0) ? bgmu[d] + __expf(bgls[d]) * nbg[bt * 64 + d]
                              : fmu[d]  + __expf(fls[d])  * nfg[(bt * 6 + s - 1) * 64 + d];
            sL[t] = sinit0;
            if (t < 192) {
                int i2 = 256 + t; int s2 = i2 >> 6, d2 = i2 & 63;   // s2 in 4..6
                sinit1 = fmu[d2] + __expf(fls[d2]) * nfg[(bt * 6 + s2 - 1) * 64 + d2];
                sL[i2] = sinit1;
            }
        }
        __syncthreads();
        for (int s2 = w; s2 < 7; s2 += 4) {
            float v = sL[s2 * 64 + lane], mu, var;
            wave_stats64(v, mu, var);
            xnqS[s2 * 64 + lane] = (v - mu) * rsqrtf(var + LN_EPS) * sg[lane] + sb[lane];
        }
        __syncthreads();
#pragma unroll
        for (int p = 0; p < 2; ++p) {
            int i = p * 256 + t;
            if (i < 448) {
                int s = i >> 6, e = i & 63; float a = 0.f;
#pragma unroll 8
                for (int d = 0; d < 64; ++d) a += xnqS[s * 64 + d] * Wq[e * 64 + d];
                qS[i] = a;
            }
        }
        __syncthreads();
#pragma unroll
        for (int p = 0; p < 2; ++p) {
            int i = p * 256 + t;
            if (i < 448) {
                int s = i >> 6, t2 = i & 63; float a = 0.f;
#pragma unroll 8
                for (int e = 0; e < 64; ++e) a += qS[s * 64 + e] * Wk[e * 64 + t2];
                qk0S[i] = 0.125f * a;
            } else {
                qk0S[i] = 0.f;   // slot 7
            }
        }
        __syncthreads();
    }

    // ---- A-frags: qk^T, slots x dims ----
    short8 aq0 = {}, aq1 = {};
    if (it == 0) {
        if (m < 8) {
#pragma unroll
            for (int j = 0; j < 8; ++j) {
                aq0[j] = (short)f2bf(qk0S[m * 64 + qd * 8 + j]);
                aq1[j] = (short)f2bf(qk0S[m * 64 + 32 + qd * 8 + j]);
            }
        }
        __syncthreads();   // qk0S region about to be overwritten by xnT
    } else {
        if (m < 8) {
            const ushortT* qb = qk_bf + bt * 512 + m * 64 + qd * 8;
            aq0 = *reinterpret_cast<const short8*>(qb);
            aq1 = *reinterpret_cast<const short8*>(qb + 32);
        }
    }

    // ---- xw: LN(x) (it0, + write xnf) or load xnf ----
    unsigned xw[2][8];
    if (it == 0) {
        float4 g4[2][2], b4[2][2];
#pragma unroll
        for (int c = 0; c < 2; ++c) {
            g4[c][0] = *reinterpret_cast<const float4*>(lngi + c * 32 + qd * 8);
            g4[c][1] = *reinterpret_cast<const float4*>(lngi + c * 32 + qd * 8 + 4);
            b4[c][0] = *reinterpret_cast<const float4*>(lnbi + c * 32 + qd * 8);
            b4[c][1] = *reinterpret_cast<const float4*>(lnbi + c * 32 + qd * 8 + 4);
        }
#pragma unroll
        for (int tile = 0; tile < 2; ++tile) {
            long R = (long)ck * 128 + w * 32 + tile * 16 + m;
            float4 xa[2][2];
#pragma unroll
            for (int c = 0; c < 2; ++c) {
                xa[c][0] = *reinterpret_cast<const float4*>(x + R * 64 + c * 32 + qd * 8);
                xa[c][1] = *reinterpret_cast<const float4*>(x + R * 64 + c * 32 + qd * 8 + 4);
            }
            float s1 = 0.f, s2 = 0.f;
#pragma unroll
            for (int c = 0; c < 2; ++c)
#pragma unroll
                for (int h = 0; h < 2; ++h) {
                    float4 v = xa[c][h];
                    s1 += v.x + v.y + v.z + v.w;
                    s2 += v.x * v.x + v.y * v.y + v.z * v.z + v.w * v.w;
                }
            s1 += __shfl_xor(s1, 16); s2 += __shfl_xor(s2, 16);
            s1 += __shfl_xor(s1, 32); s2 += __shfl_xor(s2, 32);
            float mu = s1 * (1.f / 64.f);
            float var = s2 * (1.f / 64.f) - mu * mu;
            float rs = rsqrtf(var + LN_EPS);
#pragma unroll
            for (int c = 0; c < 2; ++c)
#pragma unroll
                for (int h = 0; h < 2; ++h) {
                    float n0 = (xa[c][h].x - mu) * rs * g4[c][h].x + b4[c][h].x;
                    float n1 = (xa[c][h].y - mu) * rs * g4[c][h].y + b4[c][h].y;
                    float n2 = (xa[c][h].z - mu) * rs * g4[c][h].z + b4[c][h].z;
                    float n3 = (xa[c][h].w - mu) * rs * g4[c][h].w + b4[c][h].w;
                    xw[tile][c * 4 + h * 2]     = (unsigned)f2bf(n0) | ((unsigned)f2bf(n1) << 16);
                    xw[tile][c * 4 + h * 2 + 1] = (unsigned)f2bf(n2) | ((unsigned)f2bf(n3) << 16);
                }
            ushortT* xp = xnf + (long)ck * 8192 + w * 2048 + tile * 1024 + lane * 16;
            *reinterpret_cast<uint4*>(xp) =
                make_uint4(xw[tile][0], xw[tile][1], xw[tile][2], xw[tile][3]);
            *reinterpret_cast<uint4*>(xp + 8) =
                make_uint4(xw[tile][4], xw[tile][5], xw[tile][6], xw[tile][7]);
        }
    } else {
#pragma unroll
        for (int tile = 0; tile < 2; ++tile) {
            const ushortT* xp = xnf + (long)ck * 8192 + w * 2048 + tile * 1024 + lane * 16;
            uint4 u0 = *reinterpret_cast<const uint4*>(xp);
            uint4 u1 = *reinterpret_cast<const uint4*>(xp + 8);
            xw[tile][0] = u0.x; xw[tile][1] = u0.y; xw[tile][2] = u0.z; xw[tile][3] = u0.w;
            xw[tile][4] = u1.x; xw[tile][5] = u1.y; xw[tile][6] = u1.z; xw[tile][7] = u1.w;
        }
    }

    // ---- scatter xn into xnT (pair-packed b32, proven R3 path) ----
#pragma unroll
    for (int tile = 0; tile < 2; ++tile) {
        int Re = (w * 32 + tile * 16 + m) & ~1;
#pragma unroll
        for (int c = 0; c < 2; ++c) {
            unsigned pt[4];
#pragma unroll
            for (int k = 0; k < 4; ++k) pt[k] = __shfl_xor(xw[tile][c * 4 + k], 1);
#pragma unroll
            for (int kk = 0; kk < 2; ++kk) {
                unsigned own = (m & 1) ? xw[tile][c * 4 + 2 + kk] : xw[tile][c * 4 + kk];
                unsigned par = (m & 1) ? pt[2 + kk] : pt[kk];
                unsigned a   = (m & 1) ? par : own;
                unsigned bb  = (m & 1) ? own : par;
                unsigned lo = (a & 0xffffu) | (bb << 16);
                unsigned hi = (a >> 16)     | (bb & 0xffff0000u);
                int e = c * 32 + qd * 8 + 2 * kk + ((m & 1) ? 4 : 0);
                *reinterpret_cast<unsigned*>(&xnT[e * 140 + Re])       = lo;
                *reinterpret_cast<unsigned*>(&xnT[(e + 1) * 140 + Re]) = hi;
            }
        }
    }

    // ---- phase 1: logits ----
    floatx4 accT0 = {0.f, 0.f, 0.f, 0.f}, accT1 = {0.f, 0.f, 0.f, 0.f};
    {
        uint4v b00 = {xw[0][0], xw[0][1], xw[0][2], xw[0][3]};
        uint4v b01 = {xw[0][4], xw[0][5], xw[0][6], xw[0][7]};
        accT0 = __builtin_amdgcn_mfma_f32_16x16x32_bf16(aq0,
                    __builtin_bit_cast(short8, b00), accT0, 0, 0, 0);
        accT0 = __builtin_amdgcn_mfma_f32_16x16x32_bf16(aq1,
                    __builtin_bit_cast(short8, b01), accT0, 0, 0, 0);
        uint4v b10 = {xw[1][0], xw[1][1], xw[1][2], xw[1][3]};
        uint4v b11 = {xw[1][4], xw[1][5], xw[1][6], xw[1][7]};
        accT1 = __builtin_amdgcn_mfma_f32_16x16x32_bf16(aq0,
                    __builtin_bit_cast(short8, b10), accT1, 0, 0, 0);
        accT1 = __builtin_amdgcn_mfma_f32_16x16x32_bf16(aq1,
                    __builtin_bit_cast(short8, b11), accT1, 0, 0, 0);
    }

    // ---- tile-split softmax ----
    float lgA[4], lgB[4];
#pragma unroll
    for (int r = 0; r < 4; ++r) {
        float hi = __shfl_xor(accT1[r], 32);
        float wk = (qd < 2) ? accT0[r] : hi;
        float pr = __shfl_xor(wk, 16);
        lgA[r] = (qd & 1) ? pr : wk;
        lgB[r] = (qd & 1) ? wk : pr;
    }
    float mx = fmaxf(fmaxf(fmaxf(lgA[0], lgA[1]), fmaxf(lgA[2], lgA[3])),
                     fmaxf(fmaxf(lgB[0], lgB[1]), lgB[2]));
    float eA[4], eB[3], sum = 0.f;
#pragma unroll
    for (int r = 0; r < 4; ++r) { eA[r] = __expf(lgA[r] - mx); sum += eA[r]; }
#pragma unroll
    for (int r = 0; r < 3; ++r) { eB[r] = __expf(lgB[r] - mx); sum += eB[r]; }
    float inv = 1.f / sum;
    int prow = w * 32 + (qd >> 1) * 16 + m;
    if ((qd & 1) == 0) {
#pragma unroll
        for (int r = 0; r < 4; ++r) p_lds[r][prow] = f2bf(eA[r] * inv + EPS_ATTN);
    } else {
#pragma unroll
        for (int r = 0; r < 3; ++r) p_lds[4 + r][prow] = f2bf(eB[r] * inv + EPS_ATTN);
    }
    __syncthreads();

    // ---- phase 2: pxn / den via MFMA ----
    short8 ones;
#pragma unroll
    for (int j = 0; j < 8; ++j) ones[j] = (short)0x3F80;
    floatx4 acc2 = {0.f, 0.f, 0.f, 0.f}, accd = {0.f, 0.f, 0.f, 0.f};
#pragma unroll
    for (int ks = 0; ks < 4; ++ks) {
        short8 ap = *reinterpret_cast<const short8*>(&p_lds[m][ks * 32 + qd * 8]);
        const ushortT* xp = xnT + (w * 16 + m) * 140 + ks * 32 + qd * 8;
        uint2 u0 = *reinterpret_cast<const uint2*>(xp);
        uint2 u1 = *reinterpret_cast<const uint2*>(xp + 4);
        uint4v bb = {u0.x, u0.y, u1.x, u1.y};
        acc2 = __builtin_amdgcn_mfma_f32_16x16x32_bf16(ap,
                   __builtin_bit_cast(short8, bb), acc2, 0, 0, 0);
        accd = __builtin_amdgcn_mfma_f32_16x16x32_bf16(ap, ones, accd, 0, 0, 0);
    }
    // ---- publish partials via MALL atomics (coherent, no fence needed) ----
    float* pac = pxn_acc + (long)(it * 128 + bt) * 448;
#pragma unroll
    for (int r = 0; r < 4; ++r) {
        int s = qd * 4 + r;
        if (s < 7) atomicAdd(&pac[s * 64 + w * 16 + m], acc2[r]);
    }
    if (w == 0 && m == 0) {
#pragma unroll
        for (int r = 0; r < 4; ++r) {
            int s = qd * 4 + r;
            if (s < 7) atomicAdd(&den_acc[(it * 128 + bt) * 8 + s], accd[r]);
        }
    }
    asm volatile("s_waitcnt vmcnt(0)" ::: "memory");   // adds ack'd at MALL
    __syncthreads();
    if (t == 0) {
        int old = __hip_atomic_fetch_add(&tick[it * 128 + bt], 1,
                                         __ATOMIC_RELAXED, __HIP_MEMORY_SCOPE_AGENT);
        winflag = (old == 31);
    }
    __syncthreads();
    if (!winflag) return;

    // ================= winner: full slot update for batch bt =================
    // hprev
    if (it == 0) {
        hpS[t] = sinit0;
        if (t < 192) hpS[256 + t] = sinit1;
    } else {
#pragma unroll
        for (int p = 0; p < 2; ++p) {
            int i = p * 256 + t;
            if (i < 448) hpS[i] = slots[(long)bt * 448 + i];
        }
    }
    // read fully-accumulated pxn / den (sc0 sc1: bypass stale local L2)
#pragma unroll
    for (int p = 0; p < 2; ++p) {
        int i = p * 256 + t;
        if (i < 448) pxnS[i] = ld_agent(&pac[i]);
    }
    if (t < 7) denS[t] = ld_agent(&den_acc[(it * 128 + bt) * 8 + t]);
    __syncthreads();
    // upd = (pxn . WvT) / den
#pragma unroll
    for (int p = 0; p < 2; ++p) {
        int i = p * 256 + t;
        if (i < 448) {
            int s = i >> 6, d = i & 63;
            float a = 0.f;
#pragma unroll 8
            for (int e = 0; e < 64; ++e) a += pxnS[s * 64 + e] * WvT[e * 64 + d];
            updS[i] = a / denS[s];
        }
    }
    __syncthreads();
    // GRU gates
#pragma unroll
    for (int p = 0; p < 6; ++p) {
        int i = p * 256 + t;
        if (i < 1344) {
            int s = i / 192, g = i % 192;
            float a = bih[g], h2 = bhh[g];
#pragma unroll 8
            for (int d = 0; d < 64; ++d) {
                a  += updS[s * 64 + d] * WihT[d * 192 + g];
                h2 += hpS[s * 64 + d]  * WhhT[d * 192 + g];
            }
            giS[i] = a; ghS[i] = h2;
        }
    }
    __syncthreads();
    // gate combine
#pragma unroll
    for (int p = 0; p < 2; ++p) {
        int i = p * 256 + t;
        if (i < 448) {
            int s = i >> 6, d = i & 63;
            float r = 1.f / (1.f + __expf(-(giS[s * 192 + d] + ghS[s * 192 + d])));
            float z = 1.f / (1.f + __expf(-(giS[s * 192 + 64 + d] + ghS[s * 192 + 64 + d])));
            float n = tanhf(giS[s * 192 + 128 + d] + r * ghS[s * 192 + 128 + d]);
            resS[i] = (1.f - z) * n + z * hpS[i];
        }
    }
    __syncthreads();
    // LN_mlp
    for (int s2 = w; s2 < 7; s2 += 4) {
        float v = resS[s2 * 64 + lane], mu, var;
        wave_stats64(v, mu, var);
        mnS[s2 * 64 + lane] = (v - mu) * rsqrtf(var + LN_EPS) * lnmg[lane] + lnmb[lane];
    }
    __syncthreads();
    // MLP1
#pragma unroll
    for (int p = 0; p < 4; ++p) {
        int i = p * 256 + t;
        if (i < 896) {
            int s = i >> 7, h1 = i & 127;
            float a = b1[h1];
#pragma unroll 8
            for (int d = 0; d < 64; ++d) a += mnS[s * 64 + d] * w1T[d * 128 + h1];
            m1S[i] = fmaxf(a, 0.f);
        }
    }
    __syncthreads();
    // MLP2 + residual
#pragma unroll
    for (int p = 0; p < 2; ++p) {
        int i = p * 256 + t;
        if (i < 448) {
            int s = i >> 6, d = i & 63;
            float a = b2[d];
#pragma unroll 8
            for (int h2 = 0; h2 < 128; ++h2) a += m1S[s * 128 + h2] * w2T[h2 * 64 + d];
            resS[i] += a;
        }
    }
    __syncthreads();
    if (it == 2) {
#pragma unroll
        for (int p = 0; p < 2; ++p) {
            int i = p * 256 + t;
            if (i < 448) outp[(long)bt * 448 + i] = resS[i];
        }
        return;
    }
#pragma unroll
    for (int p = 0; p < 2; ++p) {
        int i = p * 256 + t;
        if (i < 448) slots[(long)bt * 448 + i] = resS[i];
    }
    // slot LN -> updS (reuse)
    for (int s2 = w; s2 < 7; s2 += 4) {
        float v = resS[s2 * 64 + lane], mu, var;
        wave_stats64(v, mu, var);
        updS[s2 * 64 + lane] = (v - mu) * rsqrtf(var + LN_EPS) * sg[lane] + sb[lane];
    }
    __syncthreads();
    // q -> pxnS (reuse)
#pragma unroll
    for (int p = 0; p < 2; ++p) {
        int i = p * 256 + t;
        if (i < 448) {
            int s = i >> 6, e = i & 63;
            float a = 0.f;
#pragma unroll 8
            for (int d = 0; d < 64; ++d) a += updS[s * 64 + d] * Wq[e * 64 + d];
            pxnS[i] = a;
        }
    }
    __syncthreads();
    // qk -> qk_bf (bf16), slot 7 zeroed
#pragma unroll
    for (int p = 0; p < 2; ++p) {
        int i = p * 256 + t;
        if (i < 448) {
            int s = i >> 6, t2 = i & 63;
            float a = 0.f;
#pragma unroll 8
            for (int e = 0; e < 64; ++e) a += pxnS[s * 64 + e] * Wk[e * 64 + t2];
            qk_bf[(long)bt * 512 + i] = f2bf(0.125f * a);
        } else {
            qk_bf[(long)bt * 512 + i] = 0;
        }
    }
}

// ---------------- launcher: 4 dispatches ----------------
extern "C" void kernel_launch(void* const* d_in, const int* in_sizes, int n_in,
                              void* d_out, int out_size, void* d_ws, size_t ws_size,
                              hipStream_t stream) {
    const float* inputs    = (const float*)d_in[0];
    const float* noise_bg  = (const float*)d_in[1];
    const float* noise_fg  = (const float*)d_in[2];
    const float* ln_in_g   = (const float*)d_in[3];
    const float* ln_in_b   = (const float*)d_in[4];
    const float* ln_slot_g = (const float*)d_in[5];
    const float* ln_slot_b = (const float*)d_in[6];
    const float* ln_mlp_g  = (const float*)d_in[7];
    const float* ln_mlp_b  = (const float*)d_in[8];
    const float* Wq        = (const float*)d_in[9];
    const float* Wk        = (const float*)d_in[10];
    const float* Wv        = (const float*)d_in[11];
    const float* W_ih      = (const float*)d_in[12];
    const float* W_hh      = (const float*)d_in[13];
    const float* b_ih      = (const float*)d_in[14];
    const float* b_hh      = (const float*)d_in[15];
    const float* mlp_w1    = (const float*)d_in[16];
    const float* mlp_b1    = (const float*)d_in[17];
    const float* mlp_w2    = (const float*)d_in[18];
    const float* mlp_b2    = (const float*)d_in[19];
    const float* sbg_mu    = (const float*)d_in[20];
    const float* sbg_ls    = (const float*)d_in[21];
    const float* s_mu      = (const float*)d_in[22];
    const float* s_ls      = (const float*)d_in[23];

    char* ws = (char*)d_ws;
    size_t off = 0;
    auto alloc = [&](size_t bytes) {
        void* p = ws + off;
        off += (bytes + 255) & ~(size_t)255;
        return p;
    };
    ushortT* xnf   = (ushortT*)alloc((size_t)BB * NN * 64 * 2);   // 64 MiB bf16 xn
    float* slots   = (float*)alloc((size_t)BB * 7 * 64 * 4);
    ushortT* qk_bf = (ushortT*)alloc((size_t)BB * 512 * 2);
    float* WihT    = (float*)alloc(12288 * 4);
    float* WhhT    = (float*)alloc(12288 * 4);
    float* w1T     = (float*)alloc(8192 * 4);
    float* w2T     = (float*)alloc(8192 * 4);
    float* WvT     = (float*)alloc(4096 * 4);
    // contiguous zero region: pxn_acc + den_acc + tick (sizes all 256B-multiples)
    float* pxn_acc = (float*)alloc((size_t)3 * 128 * 448 * 4);   // 688128 B
    float* den_acc = (float*)alloc((size_t)3 * 128 * 8 * 4);     // 12288 B
    int*   tick    = (int*)alloc(384 * 4);                       // 1536 B
    if (off > ws_size) return;
    float* outp = (float*)d_out;

    prep_zero<<<862, 256, 0, stream>>>(W_ih, W_hh, mlp_w1, mlp_w2, Wv,
                                       WihT, WhhT, w1T, w2T, WvT, pxn_acc);
    for (int it = 0; it < N_ITERS; ++it) {
        attn_slot<<<4096, 256, 0, stream>>>(
            it, inputs, ln_in_g, ln_in_b, xnf, qk_bf, slots, outp,
            noise_bg, noise_fg, sbg_mu, sbg_ls, s_mu, s_ls,
            Wq, Wk, WihT, WhhT, b_ih, b_hh,
            ln_mlp_g, ln_mlp_b, w1T, mlp_b1, w2T, mlp_b2,
            WvT, ln_slot_g, ln_slot_b,
            pxn_acc, den_acc, tick);
    }
}

// Round 8
// 410.631 us; speedup vs baseline: 5.4642x; 1.8284x over previous
//
#include <hip/hip_runtime.h>

// ---------------- problem constants ----------------
#define BB 128
#define NN 4096
#define DD 64
#define SS 7
#define HH 128
#define N_ITERS 3
#define EPS_ATTN 1e-8f
#define LN_EPS 1e-5f

typedef unsigned short ushortT;
using short8  = __attribute__((ext_vector_type(8))) short;
using floatx4 = __attribute__((ext_vector_type(4))) float;
using uint4v  = __attribute__((ext_vector_type(4))) unsigned;

__device__ __forceinline__ ushortT f2bf(float f) {
    unsigned x = __builtin_bit_cast(unsigned, f);
    x = x + 0x7fff + ((x >> 16) & 1);   // RNE
    return (ushortT)(x >> 16);
}
__device__ __forceinline__ void wave_stats64(float x, float& mu, float& var) {
    float s1 = x, s2 = x * x;
#pragma unroll
    for (int off = 32; off > 0; off >>= 1) {
        s1 += __shfl_xor(s1, off);
        s2 += __shfl_xor(s2, off);
    }
    mu  = s1 * (1.f / 64.f);
    var = s2 * (1.f / 64.f) - mu * mu;
}
// device-coherent vector store (write-through to MALL); drain via vmcnt later
__device__ __forceinline__ void st_sc_f4(float* p, floatx4 v) {
    asm volatile("global_store_dwordx4 %0, %1, off sc0 sc1"
                 :: "v"(p), "v"(v) : "memory");
}
// device-coherent vector load; waitcnt fused in the SAME asm so consumers
// cannot be scheduled between load and wait (rule #18)
__device__ __forceinline__ floatx4 ld_sc_f4(const float* p) {
    floatx4 r;
    asm volatile("global_load_dwordx4 %0, %1, off sc0 sc1\n\t"
                 "s_waitcnt vmcnt(0)"
                 : "=&v"(r) : "v"(p) : "memory");
    return r;
}

// ---------------- D1: weight transposes + ticket zero ----------------
__global__ void prep_zero(const float* __restrict__ Wih, const float* __restrict__ Whh,
                          const float* __restrict__ w1, const float* __restrict__ w2,
                          const float* __restrict__ Wv,
                          float* __restrict__ WihT, float* __restrict__ WhhT,
                          float* __restrict__ w1T, float* __restrict__ w2T,
                          float* __restrict__ WvT, int* __restrict__ tick) {
    if (blockIdx.x >= 176) {
        int i = (blockIdx.x - 176) * 256 + threadIdx.x;
        if (i < 384) tick[i] = 0;
        return;
    }
    int i = blockIdx.x * 256 + threadIdx.x;   // < 45056
    if (i < 12288) {
        int e = i >> 6, d = i & 63;
        WihT[d * 192 + e] = Wih[i];
    } else if (i < 24576) {
        int j = i - 12288; int e = j >> 6, d = j & 63;
        WhhT[d * 192 + e] = Whh[j];
    } else if (i < 32768) {
        int j = i - 24576; int e = j >> 6, d = j & 63;   // w1 [128][64]
        w1T[d * 128 + e] = w1[j];
    } else if (i < 40960) {
        int j = i - 32768; int e = j >> 7, h = j & 127;  // w2 [64][128]
        w2T[h * 64 + e] = w2[j];
    } else if (i < 45056) {
        int j = i - 40960; int d = j >> 6, e = j & 63;   // Wv [d][e] -> WvT [e][d]
        WvT[e * 64 + d] = Wv[j];
    }
}

// ---------------- D2/D3/D4: attn (8 chunks/block) + ticket-gated slot tail ----
// Grid 512, 256 thr. Block blk: batch bt=blk>>2, sub=blk&3 -> chunks
// bt*32+sub*8 .. +8. Partials accumulate in REGISTERS across the 8 chunks;
// one vectorized sc0sc1 publication per block (114 dwordx4). Relaxed agent
// ticket; last of the 4 blocks (old==3) gathers 4 partials via sc0sc1 loads
// and runs the full 7-slot GRU/LN/MLP update.
__global__ __launch_bounds__(256, 2) void attn_slot(
    int it,
    const float* __restrict__ x,
    const float* __restrict__ lngi, const float* __restrict__ lnbi,
    ushortT* __restrict__ xnf, ushortT* __restrict__ qk_bf,
    float* __restrict__ slots, float* __restrict__ outp,
    const float* __restrict__ nbg, const float* __restrict__ nfg,
    const float* __restrict__ bgmu, const float* __restrict__ bgls,
    const float* __restrict__ fmu, const float* __restrict__ fls,
    const float* __restrict__ Wq, const float* __restrict__ Wk,
    const float* __restrict__ WihT, const float* __restrict__ WhhT,
    const float* __restrict__ bih, const float* __restrict__ bhh,
    const float* __restrict__ lnmg, const float* __restrict__ lnmb,
    const float* __restrict__ w1T, const float* __restrict__ b1,
    const float* __restrict__ w2T, const float* __restrict__ b2,
    const float* __restrict__ WvT,
    const float* __restrict__ sg, const float* __restrict__ sb,
    float* __restrict__ pxn_p, float* __restrict__ den_p,
    int* __restrict__ tick) {
    int t = threadIdx.x;
    int blk = blockIdx.x, bt = blk >> 2, sub = blk & 3;
    int w = t >> 6, lane = t & 63, m = lane & 15, qd = lane >> 4;

    // time-multiplexed LDS union (phases barrier-separated)
    __shared__ __align__(16) char smem[23424];
    ushortT* xnT = (ushortT*)smem;                           // [64*140]   attn
    ushortT (*p_lds)[136] = (ushortT(*)[136])(smem + 17920); // [16][136]  attn
    float* qk0S = (float*)smem;                              // [8][64]    it0 pre
    float* sL   = (float*)(smem + 2048);                     // [7][64]    it0 pre
    float* xnqS = (float*)(smem + 3840);                     // [7][64]    it0 pre
    float* qS   = (float*)(smem + 5632);                     // [7][64]    it0 pre
    float* pxnS = (float*)smem;                              // [7][64]    pub/tail
    float* updS = (float*)(smem + 1792);                     // [7][64]    tail
    float* hpS  = (float*)(smem + 3584);                     // [7][64]    tail
    float* giS  = (float*)(smem + 5376);                     // [7][192]   tail
    float* ghS  = (float*)(smem + 10752);                    // [7][192]   tail
    float* m1S  = (float*)(smem + 16128);                    // [7][128]   tail
    float* resS = (float*)(smem + 19712);                    // [7][64]    tail
    float* mnS  = (float*)(smem + 21504);                    // [7][64]    tail
    __shared__ __align__(16) float denS[8];
    __shared__ int winflag;

    // ---- it0: redundant slot-init + qk (per block, identical across blocks) ----
    float sinit0 = 0.f, sinit1 = 0.f;
    if (it == 0) {
        {
            int s = t >> 6, d = t & 63;
            sinit0 = (s == 0) ? bgmu[d] + __expf(bgls[d]) * nbg[bt * 64 + d]
                              : fmu[d]  + __expf(fls[d])  * nfg[(bt * 6 + s - 1) * 64 + d];
            sL[t] = sinit0;
            if (t < 192) {
                int i2 = 256 + t; int s2 = i2 >> 6, d2 = i2 & 63;   // s2 in 4..6
                sinit1 = fmu[d2] + __expf(fls[d2]) * nfg[(bt * 6 + s2 - 1) * 64 + d2];
                sL[i2] = sinit1;
            }
        }
        __syncthreads();
        for (int s2 = w; s2 < 7; s2 += 4) {
            float v = sL[s2 * 64 + lane], mu, var;
            wave_stats64(v, mu, var);
            xnqS[s2 * 64 + lane] = (v - mu) * rsqrtf(var + LN_EPS) * sg[lane] + sb[lane];
        }
        __syncthreads();
#pragma unroll
        for (int p = 0; p < 2; ++p) {
            int i = p * 256 + t;
            if (i < 448) {
                int s = i >> 6, e = i & 63; float a = 0.f;
#pragma unroll 8
                for (int d = 0; d < 64; ++d) a += xnqS[s * 64 + d] * Wq[e * 64 + d];
                qS[i] = a;
            }
        }
        __syncthreads();
#pragma unroll
        for (int p = 0; p < 2; ++p) {
            int i = p * 256 + t;
            if (i < 448) {
                int s = i >> 6, t2 = i & 63; float a = 0.f;
#pragma unroll 8
                for (int e = 0; e < 64; ++e) a += qS[s * 64 + e] * Wk[e * 64 + t2];
                qk0S[i] = 0.125f * a;
            } else {
                qk0S[i] = 0.f;   // slot 7
            }
        }
        __syncthreads();
    }

    // ---- A-frags: qk^T, slots x dims ----
    short8 aq0 = {}, aq1 = {};
    if (it == 0) {
        if (m < 8) {
#pragma unroll
            for (int j = 0; j < 8; ++j) {
                aq0[j] = (short)f2bf(qk0S[m * 64 + qd * 8 + j]);
                aq1[j] = (short)f2bf(qk0S[m * 64 + 32 + qd * 8 + j]);
            }
        }
    } else {
        if (m < 8) {
            const ushortT* qb = qk_bf + bt * 512 + m * 64 + qd * 8;
            aq0 = *reinterpret_cast<const short8*>(qb);
            aq1 = *reinterpret_cast<const short8*>(qb + 32);
        }
    }

    // LN gamma/beta hoisted (it0 only)
    float4 g4[2][2], b4[2][2];
    if (it == 0) {
#pragma unroll
        for (int c = 0; c < 2; ++c) {
            g4[c][0] = *reinterpret_cast<const float4*>(lngi + c * 32 + qd * 8);
            g4[c][1] = *reinterpret_cast<const float4*>(lngi + c * 32 + qd * 8 + 4);
            b4[c][0] = *reinterpret_cast<const float4*>(lnbi + c * 32 + qd * 8);
            b4[c][1] = *reinterpret_cast<const float4*>(lnbi + c * 32 + qd * 8 + 4);
        }
    }

    short8 ones;
#pragma unroll
    for (int j = 0; j < 8; ++j) ones[j] = (short)0x3F80;   // bf16 1.0
    floatx4 acc2 = {0.f, 0.f, 0.f, 0.f}, accd = {0.f, 0.f, 0.f, 0.f};

    // ================= 8-chunk attention loop =================
    for (int c8 = 0; c8 < 8; ++c8) {
        int ck = bt * 32 + sub * 8 + c8;
        __syncthreads();   // xnT / p_lds free (prev chunk phase2 done; it0 pre done)

        unsigned xw[2][8];
        if (it == 0) {
#pragma unroll
            for (int tile = 0; tile < 2; ++tile) {
                long R = (long)ck * 128 + w * 32 + tile * 16 + m;
                float4 xa[2][2];
#pragma unroll
                for (int c = 0; c < 2; ++c) {
                    xa[c][0] = *reinterpret_cast<const float4*>(x + R * 64 + c * 32 + qd * 8);
                    xa[c][1] = *reinterpret_cast<const float4*>(x + R * 64 + c * 32 + qd * 8 + 4);
                }
                float s1 = 0.f, s2 = 0.f;
#pragma unroll
                for (int c = 0; c < 2; ++c)
#pragma unroll
                    for (int h = 0; h < 2; ++h) {
                        float4 v = xa[c][h];
                        s1 += v.x + v.y + v.z + v.w;
                        s2 += v.x * v.x + v.y * v.y + v.z * v.z + v.w * v.w;
                    }
                s1 += __shfl_xor(s1, 16); s2 += __shfl_xor(s2, 16);
                s1 += __shfl_xor(s1, 32); s2 += __shfl_xor(s2, 32);
                float mu = s1 * (1.f / 64.f);
                float var = s2 * (1.f / 64.f) - mu * mu;
                float rs = rsqrtf(var + LN_EPS);
#pragma unroll
                for (int c = 0; c < 2; ++c)
#pragma unroll
                    for (int h = 0; h < 2; ++h) {
                        float n0 = (xa[c][h].x - mu) * rs * g4[c][h].x + b4[c][h].x;
                        float n1 = (xa[c][h].y - mu) * rs * g4[c][h].y + b4[c][h].y;
                        float n2 = (xa[c][h].z - mu) * rs * g4[c][h].z + b4[c][h].z;
                        float n3 = (xa[c][h].w - mu) * rs * g4[c][h].w + b4[c][h].w;
                        xw[tile][c * 4 + h * 2]     = (unsigned)f2bf(n0) | ((unsigned)f2bf(n1) << 16);
                        xw[tile][c * 4 + h * 2 + 1] = (unsigned)f2bf(n2) | ((unsigned)f2bf(n3) << 16);
                    }
                ushortT* xp = xnf + (long)ck * 8192 + w * 2048 + tile * 1024 + lane * 16;
                *reinterpret_cast<uint4*>(xp) =
                    make_uint4(xw[tile][0], xw[tile][1], xw[tile][2], xw[tile][3]);
                *reinterpret_cast<uint4*>(xp + 8) =
                    make_uint4(xw[tile][4], xw[tile][5], xw[tile][6], xw[tile][7]);
            }
        } else {
#pragma unroll
            for (int tile = 0; tile < 2; ++tile) {
                const ushortT* xp = xnf + (long)ck * 8192 + w * 2048 + tile * 1024 + lane * 16;
                uint4 u0 = *reinterpret_cast<const uint4*>(xp);
                uint4 u1 = *reinterpret_cast<const uint4*>(xp + 8);
                xw[tile][0] = u0.x; xw[tile][1] = u0.y; xw[tile][2] = u0.z; xw[tile][3] = u0.w;
                xw[tile][4] = u1.x; xw[tile][5] = u1.y; xw[tile][6] = u1.z; xw[tile][7] = u1.w;
            }
        }

        // scatter xn into xnT (pair-packed b32)
#pragma unroll
        for (int tile = 0; tile < 2; ++tile) {
            int Re = (w * 32 + tile * 16 + m) & ~1;
#pragma unroll
            for (int c = 0; c < 2; ++c) {
                unsigned pt[4];
#pragma unroll
                for (int k = 0; k < 4; ++k) pt[k] = __shfl_xor(xw[tile][c * 4 + k], 1);
#pragma unroll
                for (int kk = 0; kk < 2; ++kk) {
                    unsigned own = (m & 1) ? xw[tile][c * 4 + 2 + kk] : xw[tile][c * 4 + kk];
                    unsigned par = (m & 1) ? pt[2 + kk] : pt[kk];
                    unsigned a   = (m & 1) ? par : own;
                    unsigned bo  = (m & 1) ? own : par;
                    unsigned lo = (a & 0xffffu) | (bo << 16);
                    unsigned hi = (a >> 16)     | (bo & 0xffff0000u);
                    int e = c * 32 + qd * 8 + 2 * kk + ((m & 1) ? 4 : 0);
                    *reinterpret_cast<unsigned*>(&xnT[e * 140 + Re])       = lo;
                    *reinterpret_cast<unsigned*>(&xnT[(e + 1) * 140 + Re]) = hi;
                }
            }
        }

        // phase 1: logits
        floatx4 accT0 = {0.f, 0.f, 0.f, 0.f}, accT1 = {0.f, 0.f, 0.f, 0.f};
        {
            uint4v b00 = {xw[0][0], xw[0][1], xw[0][2], xw[0][3]};
            uint4v b01 = {xw[0][4], xw[0][5], xw[0][6], xw[0][7]};
            accT0 = __builtin_amdgcn_mfma_f32_16x16x32_bf16(aq0,
                        __builtin_bit_cast(short8, b00), accT0, 0, 0, 0);
            accT0 = __builtin_amdgcn_mfma_f32_16x16x32_bf16(aq1,
                        __builtin_bit_cast(short8, b01), accT0, 0, 0, 0);
            uint4v b10 = {xw[1][0], xw[1][1], xw[1][2], xw[1][3]};
            uint4v b11 = {xw[1][4], xw[1][5], xw[1][6], xw[1][7]};
            accT1 = __builtin_amdgcn_mfma_f32_16x16x32_bf16(aq0,
                        __builtin_bit_cast(short8, b10), accT1, 0, 0, 0);
            accT1 = __builtin_amdgcn_mfma_f32_16x16x32_bf16(aq1,
                        __builtin_bit_cast(short8, b11), accT1, 0, 0, 0);
        }

        // tile-split softmax
        float lgA[4], lgB[4];
#pragma unroll
        for (int r = 0; r < 4; ++r) {
            float hi = __shfl_xor(accT1[r], 32);
            float wk = (qd < 2) ? accT0[r] : hi;
            float pr = __shfl_xor(wk, 16);
            lgA[r] = (qd & 1) ? pr : wk;
            lgB[r] = (qd & 1) ? wk : pr;
        }
        float mx = fmaxf(fmaxf(fmaxf(lgA[0], lgA[1]), fmaxf(lgA[2], lgA[3])),
                         fmaxf(fmaxf(lgB[0], lgB[1]), lgB[2]));
        float eA[4], eB[3], sum = 0.f;
#pragma unroll
        for (int r = 0; r < 4; ++r) { eA[r] = __expf(lgA[r] - mx); sum += eA[r]; }
#pragma unroll
        for (int r = 0; r < 3; ++r) { eB[r] = __expf(lgB[r] - mx); sum += eB[r]; }
        float inv = 1.f / sum;
        int prow = w * 32 + (qd >> 1) * 16 + m;
        if ((qd & 1) == 0) {
#pragma unroll
            for (int r = 0; r < 4; ++r) p_lds[r][prow] = f2bf(eA[r] * inv + EPS_ATTN);
        } else {
#pragma unroll
            for (int r = 0; r < 3; ++r) p_lds[4 + r][prow] = f2bf(eB[r] * inv + EPS_ATTN);
        }
        __syncthreads();

        // phase 2: accumulate pxn / den partials in registers
#pragma unroll
        for (int ks = 0; ks < 4; ++ks) {
            short8 ap = *reinterpret_cast<const short8*>(&p_lds[m][ks * 32 + qd * 8]);
            const ushortT* xp = xnT + (w * 16 + m) * 140 + ks * 32 + qd * 8;
            uint2 u0 = *reinterpret_cast<const uint2*>(xp);
            uint2 u1 = *reinterpret_cast<const uint2*>(xp + 4);
            uint4v bb = {u0.x, u0.y, u1.x, u1.y};
            acc2 = __builtin_amdgcn_mfma_f32_16x16x32_bf16(ap,
                       __builtin_bit_cast(short8, bb), acc2, 0, 0, 0);
            accd = __builtin_amdgcn_mfma_f32_16x16x32_bf16(ap, ones, accd, 0, 0, 0);
        }
    }

    // ================= publication: one vectorized sc0sc1 block =================
    __syncthreads();   // attn LDS free
#pragma unroll
    for (int r = 0; r < 4; ++r) {
        int s = qd * 4 + r;
        if (s < 7) pxnS[s * 64 + w * 16 + m] = acc2[r];
    }
    if (w == 0 && m == 0) {
#pragma unroll
        for (int r = 0; r < 4; ++r) {
            int s = qd * 4 + r;
            if (s < 7) denS[s] = accd[r];
        }
    }
    if (t == 0) denS[7] = 0.f;
    __syncthreads();
    if (t < 112) {
        st_sc_f4(&pxn_p[blk * 448 + t * 4],
                 *reinterpret_cast<const floatx4*>(&pxnS[t * 4]));
    } else if (t == 112) {
        st_sc_f4(&den_p[blk * 8], *reinterpret_cast<const floatx4*>(&denS[0]));
    } else if (t == 113) {
        st_sc_f4(&den_p[blk * 8 + 4], *reinterpret_cast<const floatx4*>(&denS[4]));
    }
    asm volatile("s_waitcnt vmcnt(0)" ::: "memory");   // stores ack'd at MALL
    __syncthreads();
    if (t == 0) {
        int old = __hip_atomic_fetch_add(&tick[it * 128 + bt], 1,
                                         __ATOMIC_RELAXED, __HIP_MEMORY_SCOPE_AGENT);
        winflag = (old == 3);
    }
    __syncthreads();
    if (!winflag) return;

    // ================= winner: full slot update for batch bt =================
    if (it == 0) {
        hpS[t] = sinit0;
        if (t < 192) hpS[256 + t] = sinit1;
    } else {
#pragma unroll
        for (int p = 0; p < 2; ++p) {
            int i = p * 256 + t;
            if (i < 448) hpS[i] = slots[(long)bt * 448 + i];
        }
    }
    if (t < 112) {
        floatx4 a = ld_sc_f4(&pxn_p[(long)(bt * 4 + 0) * 448 + t * 4]);
#pragma unroll
        for (int p = 1; p < 4; ++p) {
            floatx4 b = ld_sc_f4(&pxn_p[(long)(bt * 4 + p) * 448 + t * 4]);
            a += b;
        }
        *reinterpret_cast<floatx4*>(&pxnS[t * 4]) = a;
    } else if (t == 112 || t == 113) {
        int o = (t - 112) * 4;
        floatx4 d = ld_sc_f4(&den_p[(bt * 4 + 0) * 8 + o]);
#pragma unroll
        for (int p = 1; p < 4; ++p) {
            floatx4 e = ld_sc_f4(&den_p[(bt * 4 + p) * 8 + o]);
            d += e;
        }
        *reinterpret_cast<floatx4*>(&denS[o]) = d;
    }
    __syncthreads();
    // upd = (pxn . WvT) / den
#pragma unroll
    for (int p = 0; p < 2; ++p) {
        int i = p * 256 + t;
        if (i < 448) {
            int s = i >> 6, d = i & 63;
            float a = 0.f;
#pragma unroll 8
            for (int e = 0; e < 64; ++e) a += pxnS[s * 64 + e] * WvT[e * 64 + d];
            updS[i] = a / denS[s];
        }
    }
    __syncthreads();
    // GRU gates
#pragma unroll
    for (int p = 0; p < 6; ++p) {
        int i = p * 256 + t;
        if (i < 1344) {
            int s = i / 192, g = i % 192;
            float a = bih[g], h2 = bhh[g];
#pragma unroll 8
            for (int d = 0; d < 64; ++d) {
                a  += updS[s * 64 + d] * WihT[d * 192 + g];
                h2 += hpS[s * 64 + d]  * WhhT[d * 192 + g];
            }
            giS[i] = a; ghS[i] = h2;
        }
    }
    __syncthreads();
    // gate combine
#pragma unroll
    for (int p = 0; p < 2; ++p) {
        int i = p * 256 + t;
        if (i < 448) {
            int s = i >> 6, d = i & 63;
            float r = 1.f / (1.f + __expf(-(giS[s * 192 + d] + ghS[s * 192 + d])));
            float z = 1.f / (1.f + __expf(-(giS[s * 192 + 64 + d] + ghS[s * 192 + 64 + d])));
            float n = tanhf(giS[s * 192 + 128 + d] + r * ghS[s * 192 + 128 + d]);
            resS[i] = (1.f - z) * n + z * hpS[i];
        }
    }
    __syncthreads();
    // LN_mlp
    for (int s2 = w; s2 < 7; s2 += 4) {
        float v = resS[s2 * 64 + lane], mu, var;
        wave_stats64(v, mu, var);
        mnS[s2 * 64 + lane] = (v - mu) * rsqrtf(var + LN_EPS) * lnmg[lane] + lnmb[lane];
    }
    __syncthreads();
    // MLP1
#pragma unroll
    for (int p = 0; p < 4; ++p) {
        int i = p * 256 + t;
        if (i < 896) {
            int s = i >> 7, h1 = i & 127;
            float a = b1[h1];
#pragma unroll 8
            for (int d = 0; d < 64; ++d) a += mnS[s * 64 + d] * w1T[d * 128 + h1];
            m1S[i] = fmaxf(a, 0.f);
        }
    }
    __syncthreads();
    // MLP2 + residual
#pragma unroll
    for (int p = 0; p < 2; ++p) {
        int i = p * 256 + t;
        if (i < 448) {
            int s = i >> 6, d = i & 63;
            float a = b2[d];
#pragma unroll 8
            for (int h2 = 0; h2 < 128; ++h2) a += m1S[s * 128 + h2] * w2T[h2 * 64 + d];
            resS[i] += a;
        }
    }
    __syncthreads();
    if (it == 2) {
#pragma unroll
        for (int p = 0; p < 2; ++p) {
            int i = p * 256 + t;
            if (i < 448) outp[(long)bt * 448 + i] = resS[i];
        }
        return;
    }
#pragma unroll
    for (int p = 0; p < 2; ++p) {
        int i = p * 256 + t;
        if (i < 448) slots[(long)bt * 448 + i] = resS[i];
    }
    // slot LN -> updS (reuse)
    for (int s2 = w; s2 < 7; s2 += 4) {
        float v = resS[s2 * 64 + lane], mu, var;
        wave_stats64(v, mu, var);
        updS[s2 * 64 + lane] = (v - mu) * rsqrtf(var + LN_EPS) * sg[lane] + sb[lane];
    }
    __syncthreads();
    // q -> pxnS (reuse)
#pragma unroll
    for (int p = 0; p < 2; ++p) {
        int i = p * 256 + t;
        if (i < 448) {
            int s = i >> 6, e = i & 63;
            float a = 0.f;
#pragma unroll 8
            for (int d = 0; d < 64; ++d) a += updS[s * 64 + d] * Wq[e * 64 + d];
            pxnS[i] = a;
        }
    }
    __syncthreads();
    // qk -> qk_bf (bf16), slot 7 zeroed
#pragma unroll
    for (int p = 0; p < 2; ++p) {
        int i = p * 256 + t;
        if (i < 448) {
            int s = i >> 6, t2 = i & 63;
            float a = 0.f;
#pragma unroll 8
            for (int e = 0; e < 64; ++e) a += pxnS[s * 64 + e] * Wk[e * 64 + t2];
            qk_bf[(long)bt * 512 + i] = f2bf(0.125f * a);
        } else {
            qk_bf[(long)bt * 512 + i] = 0;
        }
    }
}

// ---------------- launcher: 4 dispatches ----------------
extern "C" void kernel_launch(void* const* d_in, const int* in_sizes, int n_in,
                              void* d_out, int out_size, void* d_ws, size_t ws_size,
                              hipStream_t stream) {
    const float* inputs    = (const float*)d_in[0];
    const float* noise_bg  = (const float*)d_in[1];
    const float* noise_fg  = (const float*)d_in[2];
    const float* ln_in_g   = (const float*)d_in[3];
    const float* ln_in_b   = (const float*)d_in[4];
    const float* ln_slot_g = (const float*)d_in[5];
    const float* ln_slot_b = (const float*)d_in[6];
    const float* ln_mlp_g  = (const float*)d_in[7];
    const float* ln_mlp_b  = (const float*)d_in[8];
    const float* Wq        = (const float*)d_in[9];
    const float* Wk        = (const float*)d_in[10];
    const float* Wv        = (const float*)d_in[11];
    const float* W_ih      = (const float*)d_in[12];
    const float* W_hh      = (const float*)d_in[13];
    const float* b_ih      = (const float*)d_in[14];
    const float* b_hh      = (const float*)d_in[15];
    const float* mlp_w1    = (const float*)d_in[16];
    const float* mlp_b1    = (const float*)d_in[17];
    const float* mlp_w2    = (const float*)d_in[18];
    const float* mlp_b2    = (const float*)d_in[19];
    const float* sbg_mu    = (const float*)d_in[20];
    const float* sbg_ls    = (const float*)d_in[21];
    const float* s_mu      = (const float*)d_in[22];
    const float* s_ls      = (const float*)d_in[23];

    char* ws = (char*)d_ws;
    size_t off = 0;
    auto alloc = [&](size_t bytes) {
        void* p = ws + off;
        off += (bytes + 255) & ~(size_t)255;
        return p;
    };
    ushortT* xnf   = (ushortT*)alloc((size_t)BB * NN * 64 * 2);   // 64 MiB bf16 xn
    float* slots   = (float*)alloc((size_t)BB * 7 * 64 * 4);
    ushortT* qk_bf = (ushortT*)alloc((size_t)BB * 512 * 2);
    float* WihT    = (float*)alloc(12288 * 4);
    float* WhhT    = (float*)alloc(12288 * 4);
    float* w1T     = (float*)alloc(8192 * 4);
    float* w2T     = (float*)alloc(8192 * 4);
    float* WvT     = (float*)alloc(4096 * 4);
    float* pxn_p   = (float*)alloc((size_t)512 * 448 * 4);   // per-block partials
    float* den_p   = (float*)alloc((size_t)512 * 8 * 4);
    int*   tick    = (int*)alloc(384 * 4);
    if (off > ws_size) return;
    float* outp = (float*)d_out;

    prep_zero<<<178, 256, 0, stream>>>(W_ih, W_hh, mlp_w1, mlp_w2, Wv,
                                       WihT, WhhT, w1T, w2T, WvT, tick);
    for (int it = 0; it < N_ITERS; ++it) {
        attn_slot<<<512, 256, 0, stream>>>(
            it, inputs, ln_in_g, ln_in_b, xnf, qk_bf, slots, outp,
            noise_bg, noise_fg, sbg_mu, sbg_ls, s_mu, s_ls,
            Wq, Wk, WihT, WhhT, b_ih, b_hh,
            ln_mlp_g, ln_mlp_b, w1T, mlp_b1, w2T, mlp_b2,
            WvT, ln_slot_g, ln_slot_b,
            pxn_p, den_p, tick);
    }
}